// Round 13
// baseline (291.345 us; speedup 1.0000x reference)
//
#include <hip/hip_runtime.h>

typedef unsigned short u16;
typedef unsigned long long u64;
typedef __attribute__((ext_vector_type(4))) float f32x4;
typedef __attribute__((ext_vector_type(8))) short bf16x8;
typedef __attribute__((ext_vector_type(8))) u16 u16x8;
typedef __attribute__((ext_vector_type(4))) u16 u16x4v;
typedef __attribute__((ext_vector_type(2))) u64 u64x2;

#define DI __device__ __forceinline__

DI u16 f2bf(float f) {
  unsigned int x = __float_as_uint(f);
  unsigned int r = (x + 0x7fffu + ((x >> 16) & 1u)) >> 16;
  return (u16)r;
}
DI float bf2f(u16 u) { return __uint_as_float(((unsigned int)u) << 16); }
DI u64 shfl64(u64 v, int src) {
  int lo = __shfl((int)(unsigned int)(v & 0xffffffffu), src, 64);
  int hi = __shfl((int)(unsigned int)(v >> 32), src, 64);
  return ((u64)(unsigned int)hi << 32) | (u64)(unsigned int)lo;
}

// ---------------------------------------------------------------------------
// K0: pack weights + transpose masks.
// wqkvT[768][256] bf16, bias[768] f32 (k pre-scaled), owT[256][256] bf16,
// maskT*[8][64][64] f32 with maskT[n][k][q] = mask[n][q][k].
// ---------------------------------------------------------------------------
__global__ __launch_bounds__(256) void pack_kernel(
    const float* __restrict__ qw, const float* __restrict__ qb,
    const float* __restrict__ kw, const float* __restrict__ kb,
    const float* __restrict__ vw, const float* __restrict__ vb,
    const float* __restrict__ ow,
    const float* __restrict__ mw, const float* __restrict__ mh,
    u16* __restrict__ wqkvT, float* __restrict__ bias, u16* __restrict__ owT,
    float* __restrict__ maskTw, float* __restrict__ maskTh)
{
  const int r = blockIdx.x;   // 0..1279
  const int t = threadIdx.x;  // 0..255
  if (r < 768) {
    const int p = r >> 8, c = r & 255;
    const float* wsrc = p == 0 ? qw : (p == 1 ? kw : vw);
    const float sc = (p == 1) ? 0.17677669529663687f : 1.0f;  // 1/sqrt(32)
    wqkvT[r * 256 + t] = f2bf(wsrc[t * 256 + c] * sc);
    if (t == 0) {
      const float* bs = p == 0 ? qb : (p == 1 ? kb : vb);
      bias[r] = bs[c] * sc;
    }
  } else if (r < 1024) {
    const int c = r - 768;
    owT[c * 256 + t] = f2bf(ow[t * 256 + c]);
  } else {
    const int r2 = r - 1024;          // 0..255
    const int sel = r2 >> 7;          // 0: mask_w, 1: mask_h
    const int n = (r2 >> 4) & 7;
    const int k = (r2 & 15) * 4 + (t >> 6);
    const int q = t & 63;
    const float* msrc = sel ? mh : mw;
    float* mdst = sel ? maskTh : maskTw;
    mdst[(n * 64 + k) * 64 + q] = msrc[(n * 64 + q) * 64 + k];
  }
}

// ---------------------------------------------------------------------------
// K1: QKV projection + bias + RoPE. R11 compute core (verified): swapped
// MFMA -> lane owns (token=lr, 4 consecutive cols), RoPE fully in-lane,
// 3 cg iterations = q,k,v, zero drains in the MFMA loop. NEW store path:
// per-wave 64x64 bf16 LDS slab (XOR swizzle col^((tok&7)*8), conflict-free
// b128 reads), 1 drain, then 8 u16x8 stores -- each instruction covers 8
// FULL 128B lines (store law from R3/R6/R9/R11).
// ---------------------------------------------------------------------------
__global__ __launch_bounds__(256, 2) void qkv_gemm_kernel(
    const float* __restrict__ x, const u16* __restrict__ wT, const float* __restrict__ bias,
    const float* __restrict__ sinp, const float* __restrict__ cosp,
    u16* __restrict__ qr, u16* __restrict__ kr, u16* __restrict__ v)
{
  __shared__ u16 As[16384];      // 32 KB swizzled 64x256 bf16 tile
  __shared__ u16 Osl[4][4608];   // 36 KB: per-wave [64 tok][72] bf16 out slab
  const int t = threadIdx.x;
  const int wave = t >> 6, lane = t & 63;
  const int g = lane >> 4, lr = lane & 15;
  const int m0 = blockIdx.x * 64;

  {  // fused convert + stage
    char* Abw = (char*)As;
#pragma unroll
    for (int i = 0; i < 16; ++i) {
      const int c = t + 256 * i;        // f32x4 chunk, 0..4095
      const int row = c >> 6, cf = c & 63;
      const float4 xv = *reinterpret_cast<const float4*>(x + (m0 + row) * 256 + cf * 4);
      u16x4v bv;
      bv.x = f2bf(xv.x); bv.y = f2bf(xv.y); bv.z = f2bf(xv.z); bv.w = f2bf(xv.w);
      *reinterpret_cast<u16x4v*>(Abw + row * 512 + ((cf * 8) ^ ((row & 7) << 4))) = bv;
    }
  }
  __syncthreads();

  const char* Ab = (const char*)As;
  u16* Ow = &Osl[wave][0];

  for (int cg = 0; cg < 3; ++cg) {
    const int colw = cg * 256 + wave * 64;   // wave's first output col (64-aligned)
    f32x4 acc[4][4];
#pragma unroll
    for (int i = 0; i < 4; ++i)
#pragma unroll
      for (int j = 0; j < 4; ++j) acc[i][j] = (f32x4){0.f, 0.f, 0.f, 0.f};

#pragma unroll
    for (int ks = 0; ks < 8; ++ks) {
      bf16x8 af[4];
#pragma unroll
      for (int mt = 0; mt < 4; ++mt) {
        const int rr = mt * 16 + lr;
        const int cb = (ks * 64 + g * 16) ^ ((rr & 7) << 4);
        af[mt] = *reinterpret_cast<const bf16x8*>(Ab + rr * 512 + cb);
      }
#pragma unroll
      for (int nt = 0; nt < 4; ++nt) {
        const bf16x8 b =
            *reinterpret_cast<const bf16x8*>(wT + (colw + nt * 16 + lr) * 256 + ks * 32 + g * 8);
#pragma unroll
        for (int mt = 0; mt < 4; ++mt)
          acc[mt][nt] = __builtin_amdgcn_mfma_f32_16x16x32_bf16(b, af[mt], acc[mt][nt], 0, 0, 0);
      }
    }

    const int proj = cg;  // 0=q 1=k 2=v (uniform)
    u16* dst = proj == 0 ? qr : (proj == 1 ? kr : v);
    const int e0 = wave * 64;

    float4 bv4[4];
#pragma unroll
    for (int nt = 0; nt < 4; ++nt)
      bv4[nt] = *reinterpret_cast<const float4*>(bias + colw + nt * 16 + g * 4);

#pragma unroll
    for (int mt = 0; mt < 4; ++mt) {
      const int tokl = mt * 16 + lr;
      const int pos = (m0 + tokl) & 4095;          // h*64 + w
      float4 snE, csE, snO, csO;
      if (proj < 2) {
        snE = *reinterpret_cast<const float4*>(sinp + pos * 32 + g * 4);
        csE = *reinterpret_cast<const float4*>(cosp + pos * 32 + g * 4);
        snO = *reinterpret_cast<const float4*>(sinp + pos * 32 + 16 + g * 4);
        csO = *reinterpret_cast<const float4*>(cosp + pos * 32 + 16 + g * 4);
      }
#pragma unroll
      for (int nt = 0; nt < 4; ++nt) {
        const float v0 = acc[mt][nt][0] + bv4[nt].x;
        const float v1 = acc[mt][nt][1] + bv4[nt].y;
        const float v2 = acc[mt][nt][2] + bv4[nt].z;
        const float v3 = acc[mt][nt][3] + bv4[nt].w;
        u16x4v o;
        if (proj < 2) {
          const float4 sn = (nt & 1) ? snO : snE;
          const float4 cs = (nt & 1) ? csO : csE;
          o.x = f2bf(v0 * cs.x - v1 * sn.x);
          o.y = f2bf(v1 * cs.y + v0 * sn.y);
          o.z = f2bf(v2 * cs.z - v3 * sn.z);
          o.w = f2bf(v3 * cs.w + v2 * sn.w);
        } else {
          o.x = f2bf(v0); o.y = f2bf(v1); o.z = f2bf(v2); o.w = f2bf(v3);
        }
        const int col = nt * 16 + g * 4;
        *reinterpret_cast<u16x4v*>(Ow + tokl * 72 + (col ^ ((tokl & 7) * 8))) = o;
      }
    }
    asm volatile("s_waitcnt lgkmcnt(0)" ::: "memory");
#pragma unroll
    for (int r = 0; r < 8; ++r) {
      const int tokl = r * 8 + (lane >> 3);
      const int kap = lane & 7;
      const u16x8 val =
          *reinterpret_cast<const u16x8*>(Ow + tokl * 72 + ((kap ^ (tokl & 7)) * 8));
      // 8 tokens x 128B per instruction = 8 full lines
      *reinterpret_cast<u16x8*>(dst + (m0 + tokl) * 256 + e0 + kap * 8) = val;
    }
    asm volatile("s_waitcnt lgkmcnt(0)" ::: "memory");  // before next cg overwrites slab
  }
}

// ---------------------------------------------------------------------------
// K2/K3: axial attention, ALL-REGISTER softmax.
// Swapped QK^T: st = mfma(kf,qf) -> S^T, lane owns (k=kmt*16+g*4+j,
// q=qmt*16+lr). maskT is pre-transposed [n][k][q] -> coalesced adds.
// Softmax over k: 15 in-lane fmax/adds + shfl_xor(16,32). P^T packed bf16
// in-lane; PV B-fragments via shfl64 redistribution (target (g,kt) sources
// g'={2(g&1),2(g&1)+1}, kmt=2kt+(g>>1)); O^T = mfma(vb,pb) (R12-verified).
// Pbuf DELETED: LDS = Vt 40KB only -> 4 blocks/CU. O deferred in regs,
// staged through dead Vt after one barrier, stored as full-line u16x8.
// ---------------------------------------------------------------------------
__global__ __launch_bounds__(256, 2) void attn_kernel(
    const u16* __restrict__ qr, const u16* __restrict__ kr, const u16* __restrict__ vsrc,
    const float* __restrict__ maskT, u16* __restrict__ dst, const int mode)
{
  __shared__ u16 Vt[256][80];  // 40 KB transposed V; reused as O slab at end
  const int t = threadIdx.x;
  const int wave = t >> 6, lane = t & 63;
  const int g = lane >> 4, lr = lane & 15;
  const int b = blockIdx.x >> 6, o = blockIdx.x & 63;
  const int base = (mode == 0) ? (b * 4096 + o * 64) * 256 : (b * 4096 + o) * 256;
  const int ts = (mode == 0) ? 256 : 16384;

#pragma unroll
  for (int i = 0; i < 8; ++i) {
    const int c = t + 256 * i;          // 16B chunk, 0..2047
    const int tok = c >> 5, ch = c & 31;
    const u16x8 val = *reinterpret_cast<const u16x8*>(vsrc + base + tok * ts + ch * 8);
    const int tc = tok ^ ((ch & 7) * 8);
#pragma unroll
    for (int j = 0; j < 8; ++j) Vt[ch * 8 + j][tc] = val[j];
  }
  __syncthreads();

  u16x4v obf[2][4][2];  // deferred O^T fragments [hh][qmt][nd]
  const f32x4 zero = (f32x4){0.f, 0.f, 0.f, 0.f};

  for (int hh = 0; hh < 2; ++hh) {
    const int n = wave * 2 + hh;
    bf16x8 qf[4], kf[4];
#pragma unroll
    for (int mt = 0; mt < 4; ++mt) {
      qf[mt] = *reinterpret_cast<const bf16x8*>(qr + base + (mt * 16 + lr) * ts + n * 32 + g * 8);
      kf[mt] = *reinterpret_cast<const bf16x8*>(kr + base + (mt * 16 + lr) * ts + n * 32 + g * 8);
    }
    f32x4 st[4][4];  // [kmt][qmt]: S^T fragments
#pragma unroll
    for (int kmt = 0; kmt < 4; ++kmt)
#pragma unroll
      for (int qmt = 0; qmt < 4; ++qmt)
        st[kmt][qmt] = __builtin_amdgcn_mfma_f32_16x16x32_bf16(kf[kmt], qf[qmt], zero, 0, 0, 0);

    const float* mp = maskT + n * 4096;
#pragma unroll
    for (int kmt = 0; kmt < 4; ++kmt)
#pragma unroll
      for (int j = 0; j < 4; ++j) {
        const int krow = kmt * 16 + g * 4 + j;
#pragma unroll
        for (int qmt = 0; qmt < 4; ++qmt)
          st[kmt][qmt][j] += mp[krow * 64 + qmt * 16 + lr];
      }

    u64 p64[4][4];  // [kmt][qmt]: P^T bf16 x4 packed
#pragma unroll
    for (int qmt = 0; qmt < 4; ++qmt) {
      float mx = st[0][qmt][0];
#pragma unroll
      for (int kmt = 0; kmt < 4; ++kmt)
#pragma unroll
        for (int j = 0; j < 4; ++j) mx = fmaxf(mx, st[kmt][qmt][j]);
      mx = fmaxf(mx, __shfl_xor(mx, 16));
      mx = fmaxf(mx, __shfl_xor(mx, 32));
      float sum = 0.f;
#pragma unroll
      for (int kmt = 0; kmt < 4; ++kmt)
#pragma unroll
        for (int j = 0; j < 4; ++j) {
          const float p = __expf(st[kmt][qmt][j] - mx);
          st[kmt][qmt][j] = p;
          sum += p;
        }
      sum += __shfl_xor(sum, 16);
      sum += __shfl_xor(sum, 32);
      const float rs = 1.f / sum;
#pragma unroll
      for (int kmt = 0; kmt < 4; ++kmt) {
        const u64 a0 = f2bf(st[kmt][qmt][0] * rs);
        const u64 a1 = f2bf(st[kmt][qmt][1] * rs);
        const u64 a2 = f2bf(st[kmt][qmt][2] * rs);
        const u64 a3 = f2bf(st[kmt][qmt][3] * rs);
        p64[kmt][qmt] = a0 | (a1 << 16) | (a2 << 32) | (a3 << 48);
      }
    }

    f32x4 oacc[4][2];
#pragma unroll
    for (int qmt = 0; qmt < 4; ++qmt)
#pragma unroll
      for (int nd = 0; nd < 2; ++nd) oacc[qmt][nd] = zero;

    const int srcA = (g & 1) * 32 + lr;   // lane of source g' = 2*(g&1)
    const int gg = g >> 1;                // selects kmt = 2kt + gg
#pragma unroll
    for (int kt = 0; kt < 2; ++kt) {
      bf16x8 pb[4];
#pragma unroll
      for (int qmt = 0; qmt < 4; ++qmt) {
        const u64 lo0 = shfl64(p64[2 * kt + 0][qmt], srcA);
        const u64 lo1 = shfl64(p64[2 * kt + 1][qmt], srcA);
        const u64 hi0 = shfl64(p64[2 * kt + 0][qmt], srcA + 16);
        const u64 hi1 = shfl64(p64[2 * kt + 1][qmt], srcA + 16);
        u64x2 qq;
        qq.x = gg ? lo1 : lo0;
        qq.y = gg ? hi1 : hi0;
        pb[qmt] = *reinterpret_cast<bf16x8*>(&qq);
      }
#pragma unroll
      for (int nd = 0; nd < 2; ++nd) {
        const int dcol = n * 32 + nd * 16 + lr;
        const bf16x8 vb = *reinterpret_cast<const bf16x8*>(
            &Vt[dcol][(kt * 32 + g * 8) ^ (((dcol >> 3) & 7) * 8)]);
#pragma unroll
        for (int qmt = 0; qmt < 4; ++qmt)
          oacc[qmt][nd] = __builtin_amdgcn_mfma_f32_16x16x32_bf16(vb, pb[qmt], oacc[qmt][nd], 0, 0, 0);
      }
    }
#pragma unroll
    for (int qmt = 0; qmt < 4; ++qmt)
#pragma unroll
      for (int nd = 0; nd < 2; ++nd) {
        obf[hh][qmt][nd].x = f2bf(oacc[qmt][nd][0]);
        obf[hh][qmt][nd].y = f2bf(oacc[qmt][nd][1]);
        obf[hh][qmt][nd].z = f2bf(oacc[qmt][nd][2]);
        obf[hh][qmt][nd].w = f2bf(oacc[qmt][nd][3]);
      }
  }

  __syncthreads();  // Vt dead for all waves
  u16* Ow = &Vt[0][0] + wave * 4608;  // per-wave [64 tok][72] slab
#pragma unroll
  for (int hh = 0; hh < 2; ++hh)
#pragma unroll
    for (int qmt = 0; qmt < 4; ++qmt)
#pragma unroll
      for (int nd = 0; nd < 2; ++nd) {
        const int tokl = qmt * 16 + lr;
        const int col = hh * 32 + nd * 16 + g * 4;  // within wave's 64-col span
        *reinterpret_cast<u16x4v*>(Ow + tokl * 72 + (col ^ ((tokl & 7) * 8))) = obf[hh][qmt][nd];
      }
  asm volatile("s_waitcnt lgkmcnt(0)" ::: "memory");
#pragma unroll
  for (int r = 0; r < 8; ++r) {
    const int tokl = r * 8 + (lane >> 3);
    const int kap = lane & 7;
    const u16x8 val = *reinterpret_cast<const u16x8*>(Ow + tokl * 72 + ((kap ^ (tokl & 7)) * 8));
    // 8 tokens x 128B per instruction = 8 full lines (any ts: chunks 128B-aligned)
    *reinterpret_cast<u16x8*>(dst + base + tokl * ts + wave * 64 + kap * 8) = val;
  }
}

// ---------------------------------------------------------------------------
// K4: depthwise 5x5 conv (LePE). thread = 4 consecutive w-pixels x 8 channels.
// ---------------------------------------------------------------------------
__global__ __launch_bounds__(256) void lepe_kernel(
    const u16* __restrict__ v, const float* __restrict__ cw, const float* __restrict__ cb,
    u16* __restrict__ lepe)
{
  const int t = threadIdx.x;
  const int cg = t & 31, pg = t >> 5;     // 32 channel-groups x 8 pixel-groups
  const int c0 = cg * 8;
  const int rowi = blockIdx.x >> 1;       // b*64 + h, 0..1023
  const int w0 = (blockIdx.x & 1) * 32 + pg * 4;
  const int h = rowi & 63;

  float acc[4][8];
#pragma unroll
  for (int p = 0; p < 4; ++p)
#pragma unroll
    for (int j = 0; j < 8; ++j) acc[p][j] = 0.f;

#pragma unroll
  for (int dy = 0; dy < 5; ++dy) {
    const int hh = h + dy - 2;
    if ((unsigned)hh >= 64u) continue;
    const u16* vrow = v + (size_t)(rowi + dy - 2) * 64 * 256 + c0;
    float fin[8][8];
#pragma unroll
    for (int i = 0; i < 8; ++i) {
      const int ww = w0 - 2 + i;
      if ((unsigned)ww < 64u) {
        const u16x8 val = *reinterpret_cast<const u16x8*>(vrow + ww * 256);
#pragma unroll
        for (int j = 0; j < 8; ++j) fin[i][j] = bf2f(val[j]);
      } else {
#pragma unroll
        for (int j = 0; j < 8; ++j) fin[i][j] = 0.f;
      }
    }
#pragma unroll
    for (int dx = 0; dx < 5; ++dx) {
      const float* wp = cw + (dy * 5 + dx) * 256 + c0;
      const float4 wA = *reinterpret_cast<const float4*>(wp);
      const float4 wB = *reinterpret_cast<const float4*>(wp + 4);
      const float wv[8] = {wA.x, wA.y, wA.z, wA.w, wB.x, wB.y, wB.z, wB.w};
#pragma unroll
      for (int p = 0; p < 4; ++p)
#pragma unroll
        for (int j = 0; j < 8; ++j)
          acc[p][j] += fin[p + dx][j] * wv[j];
    }
  }

#pragma unroll
  for (int p = 0; p < 4; ++p) {
    u16x8 r;
#pragma unroll
    for (int j = 0; j < 8; ++j) r[j] = f2bf(acc[p][j] + cb[c0 + j]);
    *reinterpret_cast<u16x8*>(lepe + ((size_t)rowi * 64 + w0 + p) * 256 + c0) = r;
  }
}

// ---------------------------------------------------------------------------
// K5: out = (attn_out + lepe) @ out_w + out_b, swapped-operand MFMA:
// lane owns (token=lr, 4 consecutive cols) -> float4 fp32 stores (full lines
// in 2 adjacent instrs per 32-col wave span). (256,2): no spill.
// ---------------------------------------------------------------------------
__global__ __launch_bounds__(256, 2) void out_gemm_kernel(
    const u16* __restrict__ ao, const u16* __restrict__ lep, const u16* __restrict__ owT,
    const float* __restrict__ ob, float* __restrict__ out)
{
  __shared__ u16 As[16384];  // 32 KB
  const int t = threadIdx.x;
  const int wave = t >> 6, lane = t & 63;
  const int g = lane >> 4, lr = lane & 15;
  const int m0 = blockIdx.x * 64;

  char* Abw = (char*)As;
#pragma unroll
  for (int i = 0; i < 8; ++i) {
    const int c = t + 256 * i;          // 16B chunk, 0..2047
    const int row = c >> 5, bc = (c & 31) << 4;
    const int off = (m0 + row) * 256 + (c & 31) * 8;
    const u16x8 a = *reinterpret_cast<const u16x8*>(ao + off);
    const u16x8 l = *reinterpret_cast<const u16x8*>(lep + off);
    u16x8 s;
#pragma unroll
    for (int j = 0; j < 8; ++j) s[j] = f2bf(bf2f(a[j]) + bf2f(l[j]));
    *reinterpret_cast<u16x8*>(Abw + row * 512 + (bc ^ ((row & 7) << 4))) = s;
  }
  __syncthreads();

  const char* Ab = (const char*)As;
  for (int cg = 0; cg < 2; ++cg) {
    const int c0w = cg * 128 + wave * 32;
    f32x4 acc[4][2];
#pragma unroll
    for (int i = 0; i < 4; ++i)
#pragma unroll
      for (int j = 0; j < 2; ++j) acc[i][j] = (f32x4){0.f, 0.f, 0.f, 0.f};

#pragma unroll
    for (int ks = 0; ks < 8; ++ks) {
      bf16x8 af[4];
#pragma unroll
      for (int mt = 0; mt < 4; ++mt) {
        const int rr = mt * 16 + lr;
        const int cb = (ks * 64 + g * 16) ^ ((rr & 7) << 4);
        af[mt] = *reinterpret_cast<const bf16x8*>(Ab + rr * 512 + cb);
      }
#pragma unroll
      for (int nt = 0; nt < 2; ++nt) {
        const bf16x8 b =
            *reinterpret_cast<const bf16x8*>(owT + (c0w + nt * 16 + lr) * 256 + ks * 32 + g * 8);
#pragma unroll
        for (int mt = 0; mt < 4; ++mt)
          acc[mt][nt] = __builtin_amdgcn_mfma_f32_16x16x32_bf16(b, af[mt], acc[mt][nt], 0, 0, 0);
      }
    }

#pragma unroll
    for (int mt = 0; mt < 4; ++mt) {
      const int tok = m0 + mt * 16 + lr;
#pragma unroll
      for (int nt = 0; nt < 2; ++nt) {
        const int col0 = c0w + nt * 16 + g * 4;
        const float4 ob4 = *reinterpret_cast<const float4*>(ob + col0);
        float4 o;
        o.x = acc[mt][nt][0] + ob4.x;
        o.y = acc[mt][nt][1] + ob4.y;
        o.z = acc[mt][nt][2] + ob4.z;
        o.w = acc[mt][nt][3] + ob4.w;
        *reinterpret_cast<float4*>(out + tok * 256 + col0) = o;
      }
    }
  }
}

// ---------------------------------------------------------------------------
extern "C" void kernel_launch(void* const* d_in, const int* in_sizes, int n_in,
                              void* d_out, int out_size, void* d_ws, size_t ws_size,
                              hipStream_t stream)
{
  const float* x      = (const float*)d_in[0];
  const float* sinp   = (const float*)d_in[1];
  const float* cosp   = (const float*)d_in[2];
  const float* mask_h = (const float*)d_in[3];
  const float* mask_w = (const float*)d_in[4];
  const float* q_w    = (const float*)d_in[5];
  const float* q_b    = (const float*)d_in[6];
  const float* k_w    = (const float*)d_in[7];
  const float* k_b    = (const float*)d_in[8];
  const float* v_w    = (const float*)d_in[9];
  const float* v_b    = (const float*)d_in[10];
  const float* lepe_w = (const float*)d_in[11];
  const float* lepe_b = (const float*)d_in[12];
  const float* out_w  = (const float*)d_in[13];
  const float* out_b  = (const float*)d_in[14];

  unsigned char* ws = (unsigned char*)d_ws;
  const size_t SZ = 33554432;  // 65536*256*2 bytes
  u16* qr    = (u16*)(ws);
  u16* kr    = (u16*)(ws + SZ);
  u16* vv    = (u16*)(ws + 2 * SZ);
  u16* v1    = (u16*)(ws + 3 * SZ);
  u16* lepe  = (u16*)(ws + 4 * SZ);
  u16* wqkvT = (u16*)(ws + 5 * SZ);
  u16* owT   = (u16*)(ws + 5 * SZ + 393216);
  float* bias   = (float*)(ws + 5 * SZ + 524288);
  float* maskTw = (float*)(ws + 5 * SZ + 528384);
  float* maskTh = (float*)(ws + 5 * SZ + 659456);
  u16* attn_out = vv;  // v is dead after conv + attnW

  pack_kernel<<<1280, 256, 0, stream>>>(q_w, q_b, k_w, k_b, v_w, v_b, out_w,
                                        mask_w, mask_h, wqkvT, bias, owT, maskTw, maskTh);
  qkv_gemm_kernel<<<1024, 256, 0, stream>>>(x, wqkvT, bias, sinp, cosp, qr, kr, vv);
  lepe_kernel<<<2048, 256, 0, stream>>>(vv, lepe_w, lepe_b, lepe);
  attn_kernel<<<1024, 256, 0, stream>>>(qr, kr, vv, maskTw, v1, 0);
  attn_kernel<<<1024, 256, 0, stream>>>(qr, kr, v1, maskTh, attn_out, 1);
  out_gemm_kernel<<<1024, 256, 0, stream>>>(attn_out, lepe, owT, out_b, (float*)d_out);
}